// Round 3
// baseline (183.912 us; speedup 1.0000x reference)
//
#include <hip/hip_runtime.h>
#include <hip/hip_bf16.h>

typedef __attribute__((ext_vector_type(8))) short bf16x8;
typedef __attribute__((ext_vector_type(4))) float f32x4;
typedef __hip_bfloat16 bf16;

#define NROWS 8192
#define DIN   2048
#define DD    768
#define CCLS  100
#define BTROWS 896   // 768 P rows + 100 muP rows + 28 zero pad

// monotone float->uint key for atomicMax on signed floats
__device__ __forceinline__ unsigned fkey(float f) {
  unsigned b = __float_as_uint(f);
  return (b & 0x80000000u) ? ~b : (b | 0x80000000u);
}
__device__ __forceinline__ float fdecode(unsigned k) {
  unsigned b = (k & 0x80000000u) ? (k ^ 0x80000000u) : ~k;
  return __uint_as_float(b);
}

// ---------------- prep kernels ----------------

// x f32 -> bf16, 8 elems/thread
__global__ void k_convert_x(const float* __restrict__ x, bf16* __restrict__ xb) {
  long i = ((long)blockIdx.x * 256 + threadIdx.x) * 8;
  float4 v0 = *(const float4*)(x + i);
  float4 v1 = *(const float4*)(x + i + 4);
  union { bf16 h[8]; bf16x8 v; } t;
  t.h[0] = __float2bfloat16(v0.x); t.h[1] = __float2bfloat16(v0.y);
  t.h[2] = __float2bfloat16(v0.z); t.h[3] = __float2bfloat16(v0.w);
  t.h[4] = __float2bfloat16(v1.x); t.h[5] = __float2bfloat16(v1.y);
  t.h[6] = __float2bfloat16(v1.z); t.h[7] = __float2bfloat16(v1.w);
  *(bf16x8*)(xb + i) = t.v;
}

// W [2048,768] f32 -> Wt [768,2048] bf16 (tiled transpose)
__global__ void k_transpose_W(const float* __restrict__ W, bf16* __restrict__ Wt) {
  __shared__ float tile[32][33];
  int tx = threadIdx.x & 31;
  int ty = threadIdx.x >> 5;          // 0..7
  int n0 = blockIdx.x * 32;
  int k0 = blockIdx.y * 32;
#pragma unroll
  for (int i = 0; i < 4; ++i)
    tile[ty + 8*i][tx] = W[(long)(k0 + ty + 8*i) * DD + n0 + tx];
  __syncthreads();
#pragma unroll
  for (int i = 0; i < 4; ++i)
    Wt[(long)(n0 + ty + 8*i) * DIN + k0 + tx] = __float2bfloat16(tile[tx][ty + 8*i]);
}

// P f32 -> BT rows [0,768); zero pad rows [868,896); hm pads [100,128) = +1e30
__global__ void k_convert_P(const float* __restrict__ P, bf16* __restrict__ BT,
                            float* __restrict__ halfmPm) {
  int id = blockIdx.x * 256 + threadIdx.x;     // 0 .. 896*768-1
  int r = id / DD;
  if (r < DD)                BT[id] = __float2bfloat16(P[id]);
  else if (r >= DD + CCLS)   BT[id] = __float2bfloat16(0.f);
  if (id >= CCLS && id < 128) halfmPm[id] = 1e30f;
}

// block (c, j): cols [j*256, j*256+256) of muP[c] = mu[c] @ P; partial 0.5*mu.muP -> atomicAdd hm[c]
__global__ __launch_bounds__(256) void k_prep_mu(const float* __restrict__ mu,
                                                 const float* __restrict__ P,
                                                 bf16* __restrict__ BT,
                                                 float* __restrict__ halfmPm) {
  __shared__ float muL[DD];
  __shared__ float red[256];
  const int tid = threadIdx.x;
  const int c = blockIdx.x;
  const int j = blockIdx.y;
  for (int i = tid; i < DD; i += 256) muL[i] = mu[(long)c * DD + i];
  __syncthreads();
  const int col = j * 256 + tid;
  float a = 0.f;
  for (int d = 0; d < DD; ++d) a += muL[d] * P[(long)d * DD + col];
  BT[(long)(DD + c) * DD + col] = __float2bfloat16(a);
  red[tid] = a * muL[col];
  __syncthreads();
  for (int s = 128; s > 0; s >>= 1) {
    if (tid < s) red[tid] += red[tid + s];
    __syncthreads();
  }
  if (tid == 0) atomicAdd(&halfmPm[c], 0.5f * red[0]);
}

// ---------------- GEMM core: BM=128, BN=128, BK=64, 8 waves (512 thr) ----------------
// Wave grid 4x2: each wave owns 32 rows x 64 cols -> acc[2][4].
// A [M,K] row-major bf16, B^T [N,K] row-major bf16; staged via global_load_lds w=16.
// LDS: As[128][64] 16KB, Bs[128][64] 16KB. 32 chunks of 1KB (8 rows), 4 per wave.

template<int LDK>
__device__ __forceinline__ void gemm_tile_mainloop(
    const bf16* __restrict__ A, const bf16* __restrict__ B,
    long rowA0, long rowB0, bf16* As, bf16* Bs, f32x4 acc[2][4])
{
  const int tid  = threadIdx.x;
  const int lane = tid & 63;
  const int w    = tid >> 6;            // 0..7
  const int wrow = w >> 1, wcol = w & 1;
  const int fr = lane & 15, fq = lane >> 4;
  const int sr = lane >> 3;             // staging row within 8-row chunk
  const int sc = (lane & 7) * 8;        // staging col offset (8 bf16 = 16B)

  for (int kt = 0; kt < LDK; kt += 64) {
#pragma unroll
    for (int i = 0; i < 4; ++i) {
      const int c = w * 4 + i;          // wave-uniform chunk id 0..31
      if (c < 16) {                     // A chunk: rows c*8 .. c*8+8
        const bf16* g = A + (rowA0 + c * 8 + sr) * (long)LDK + kt + sc;
        __builtin_amdgcn_global_load_lds(
            (const __attribute__((address_space(1))) unsigned int*)g,
            (__attribute__((address_space(3))) unsigned int*)(As + c * 512), 16, 0, 0);
      } else {                          // B chunk
        const int cb = c - 16;
        const bf16* g = B + (rowB0 + cb * 8 + sr) * (long)LDK + kt + sc;
        __builtin_amdgcn_global_load_lds(
            (const __attribute__((address_space(1))) unsigned int*)g,
            (__attribute__((address_space(3))) unsigned int*)(Bs + cb * 512), 16, 0, 0);
      }
    }
    __syncthreads();   // compiler drains vmcnt before s_barrier
#pragma unroll
    for (int kk = 0; kk < 64; kk += 32) {
      bf16x8 av[2], bv[4];
#pragma unroll
      for (int m = 0; m < 2; ++m)
        av[m] = *(const bf16x8*)(As + (wrow * 32 + m * 16 + fr) * 64 + kk + fq * 8);
#pragma unroll
      for (int n = 0; n < 4; ++n)
        bv[n] = *(const bf16x8*)(Bs + (wcol * 64 + n * 16 + fr) * 64 + kk + fq * 8);
#pragma unroll
      for (int m = 0; m < 2; ++m)
#pragma unroll
        for (int n = 0; n < 4; ++n)
          acc[m][n] = __builtin_amdgcn_mfma_f32_16x16x32_bf16(av[m], bv[n], acc[m][n], 0, 0, 0);
    }
    __syncthreads();
  }
}

// GEMM1: zb = xb @ Wt^T   [8192,2048]x[768,2048]^T -> bf16 [8192,768]
__global__ __launch_bounds__(512, 6) void k_gemm1(const bf16* __restrict__ xb,
                                                  const bf16* __restrict__ Wt,
                                                  bf16* __restrict__ zb) {
  __shared__ __align__(16) bf16 As[128 * 64];
  __shared__ __align__(16) bf16 Bs[128 * 64];
  f32x4 acc[2][4];
#pragma unroll
  for (int m = 0; m < 2; ++m)
#pragma unroll
    for (int n = 0; n < 4; ++n) acc[m][n] = (f32x4){0.f, 0.f, 0.f, 0.f};
  const long bm = blockIdx.y, bn = blockIdx.x;
  gemm_tile_mainloop<DIN>(xb, Wt, bm * 128, bn * 128, As, Bs, acc);
  const int tid = threadIdx.x, lane = tid & 63, w = tid >> 6;
  const int wrow = w >> 1, wcol = w & 1, fr = lane & 15, fq = lane >> 4;
#pragma unroll
  for (int m = 0; m < 2; ++m)
#pragma unroll
    for (int n = 0; n < 4; ++n)
#pragma unroll
      for (int j = 0; j < 4; ++j) {
        long row = bm * 128 + wrow * 32 + m * 16 + fq * 4 + j;
        long col = bn * 128 + wcol * 64 + n * 16 + fr;
        zb[row * DD + col] = __float2bfloat16(acc[m][n][j]);
      }
}

// GEMM2: out2 = zb @ BT^T, BT = [P | muP | 0] as [896,768].
// bn<6: zP tile -> rowdot with zb -> atomicAdd zPz[row]
// bn==6: score tile -> max_c(s - halfmPm[c]) -> smax_u[row]
__global__ __launch_bounds__(512, 6) void k_gemm2(const bf16* __restrict__ zb,
                                                  const bf16* __restrict__ BT,
                                                  const float* __restrict__ halfmPm,
                                                  float* __restrict__ zPz,
                                                  unsigned* __restrict__ smax_u) {
  __shared__ __align__(16) bf16 As[128 * 64];
  __shared__ __align__(16) bf16 Bs[128 * 64];
  __shared__ float sred[2][128];
  f32x4 acc[2][4];
#pragma unroll
  for (int m = 0; m < 2; ++m)
#pragma unroll
    for (int n = 0; n < 4; ++n) acc[m][n] = (f32x4){0.f, 0.f, 0.f, 0.f};
  const long bm = blockIdx.y, bn = blockIdx.x;
  gemm_tile_mainloop<DD>(zb, BT, bm * 128, bn * 128, As, Bs, acc);
  const int tid = threadIdx.x, lane = tid & 63, w = tid >> 6;
  const int wrow = w >> 1, wcol = w & 1, fr = lane & 15, fq = lane >> 4;
  const long row0 = bm * 128 + wrow * 32;

  if (bn < 6) {
    float p[2][4];
#pragma unroll
    for (int m = 0; m < 2; ++m)
#pragma unroll
      for (int j = 0; j < 4; ++j) p[m][j] = 0.f;
#pragma unroll
    for (int m = 0; m < 2; ++m)
#pragma unroll
      for (int n = 0; n < 4; ++n)
#pragma unroll
        for (int j = 0; j < 4; ++j) {
          long row = row0 + m * 16 + fq * 4 + j;
          long col = bn * 128 + wcol * 64 + n * 16 + fr;
          p[m][j] += acc[m][n][j] * __bfloat162float(zb[row * DD + col]);
        }
#pragma unroll
    for (int m = 0; m < 2; ++m)
#pragma unroll
      for (int j = 0; j < 4; ++j) {
        float v = p[m][j];
        v += __shfl_xor(v, 1, 64);
        v += __shfl_xor(v, 2, 64);
        v += __shfl_xor(v, 4, 64);
        v += __shfl_xor(v, 8, 64);
        if (fr == 0)
          atomicAdd(&zPz[row0 + m * 16 + fq * 4 + j], v);
      }
  } else {
    float hm[4];
#pragma unroll
    for (int n = 0; n < 4; ++n) hm[n] = halfmPm[wcol * 64 + n * 16 + fr];
#pragma unroll
    for (int m = 0; m < 2; ++m)
#pragma unroll
      for (int j = 0; j < 4; ++j) {
        float v = fmaxf(fmaxf(acc[m][0][j] - hm[0], acc[m][1][j] - hm[1]),
                        fmaxf(acc[m][2][j] - hm[2], acc[m][3][j] - hm[3]));
        v = fmaxf(v, __shfl_xor(v, 1, 64));
        v = fmaxf(v, __shfl_xor(v, 2, 64));
        v = fmaxf(v, __shfl_xor(v, 4, 64));
        v = fmaxf(v, __shfl_xor(v, 8, 64));
        if (fr == 0) sred[wcol][wrow * 32 + m * 16 + fq * 4 + j] = v;
      }
    __syncthreads();
    if (tid < 128) smax_u[bm * 128 + tid] = fkey(fmaxf(sred[0][tid], sred[1][tid]));
  }
}

__global__ void k_final(const unsigned* __restrict__ smax_u, const float* __restrict__ zPz,
                        float* __restrict__ out) {
  int i = blockIdx.x * 256 + threadIdx.x;
  if (i < NROWS) out[i] = fdecode(smax_u[i]) - 0.5f * zPz[i];
}

// ---------------- launch ----------------

extern "C" void kernel_launch(void* const* d_in, const int* in_sizes, int n_in,
                              void* d_out, int out_size, void* d_ws, size_t ws_size,
                              hipStream_t stream) {
  const float* x  = (const float*)d_in[0];
  const float* W  = (const float*)d_in[1];
  const float* mu = (const float*)d_in[2];
  const float* P  = (const float*)d_in[3];
  float* out = (float*)d_out;

  char* ws = (char*)d_ws;
  bf16*     xb     = (bf16*)(ws);                       // 33,554,432
  bf16*     Wt     = (bf16*)(ws + 33554432);            //  3,145,728
  bf16*     BT     = (bf16*)(ws + 36700160);            //  1,376,256
  bf16*     zb     = (bf16*)(ws + 38076416);            // 12,582,912
  float*    hm     = (float*)(ws + 50659328);           // 128*4
  float*    zPz    = (float*)(ws + 50659840);           // 8192*4
  unsigned* smax_u = (unsigned*)(ws + 50692608);        // 8192*4

  hipMemsetAsync(zPz, 0, NROWS * sizeof(float), stream);
  hipMemsetAsync(hm, 0, 128 * sizeof(float), stream);
  k_convert_x  <<<8192, 256, 0, stream>>>(x, xb);
  k_transpose_W<<<dim3(24, 64), 256, 0, stream>>>(W, Wt);
  k_convert_P  <<<2688, 256, 0, stream>>>(P, BT, hm);
  k_prep_mu    <<<dim3(CCLS, 3), 256, 0, stream>>>(mu, P, BT, hm);
  k_gemm1      <<<dim3(6, 64), 512, 0, stream>>>(xb, Wt, zb);
  k_gemm2      <<<dim3(7, 64), 512, 0, stream>>>(zb, BT, hm, zPz, smax_u);
  k_final      <<<32, 256, 0, stream>>>(smax_u, zPz, out);
}

// Round 4
// 126.068 us; speedup vs baseline: 1.4588x; 1.4588x over previous
//
#include <hip/hip_runtime.h>
#include <hip/hip_bf16.h>

typedef __attribute__((ext_vector_type(8))) short bf16x8;
typedef __attribute__((ext_vector_type(4))) float f32x4;
typedef __hip_bfloat16 bf16;

#define NROWS 8192
#define DIN   2048
#define DD    768
#define CCLS  100

// ---------------- prep kernels ----------------

// x f32 -> bf16, 8 elems/thread
__global__ void k_convert_x(const float* __restrict__ x, bf16* __restrict__ xb) {
  long i = ((long)blockIdx.x * 256 + threadIdx.x) * 8;
  float4 v0 = *(const float4*)(x + i);
  float4 v1 = *(const float4*)(x + i + 4);
  union { bf16 h[8]; bf16x8 v; } t;
  t.h[0] = __float2bfloat16(v0.x); t.h[1] = __float2bfloat16(v0.y);
  t.h[2] = __float2bfloat16(v0.z); t.h[3] = __float2bfloat16(v0.w);
  t.h[4] = __float2bfloat16(v1.x); t.h[5] = __float2bfloat16(v1.y);
  t.h[6] = __float2bfloat16(v1.z); t.h[7] = __float2bfloat16(v1.w);
  *(bf16x8*)(xb + i) = t.v;
}

// W [2048,768] f32 -> Wt [768,2048] bf16 (tiled transpose)
__global__ void k_transpose_W(const float* __restrict__ W, bf16* __restrict__ Wt) {
  __shared__ float tile[32][33];
  int tx = threadIdx.x & 31;
  int ty = threadIdx.x >> 5;          // 0..7
  int n0 = blockIdx.x * 32;
  int k0 = blockIdx.y * 32;
#pragma unroll
  for (int i = 0; i < 4; ++i)
    tile[ty + 8*i][tx] = W[(long)(k0 + ty + 8*i) * DD + n0 + tx];
  __syncthreads();
#pragma unroll
  for (int i = 0; i < 4; ++i)
    Wt[(long)(n0 + ty + 8*i) * DIN + k0 + tx] = __float2bfloat16(tile[tx][ty + 8*i]);
}

// P f32 -> BT rows [0,768); zero pad rows [868,896); hm pads [100,128) = +1e30
__global__ void k_convert_P(const float* __restrict__ P, bf16* __restrict__ BT,
                            float* __restrict__ halfmPm) {
  int id = blockIdx.x * 256 + threadIdx.x;     // 0 .. 896*768-1
  int r = id / DD;
  if (r < DD)                BT[id] = __float2bfloat16(P[id]);
  else if (r >= DD + CCLS)   BT[id] = __float2bfloat16(0.f);
  if (id >= CCLS && id < 128) halfmPm[id] = 1e30f;
}

// block (c, j): cols [j*256, j*256+256) of muP[c] = mu[c] @ P; partial 0.5*mu.muP -> atomicAdd hm[c]
__global__ __launch_bounds__(256) void k_prep_mu(const float* __restrict__ mu,
                                                 const float* __restrict__ P,
                                                 bf16* __restrict__ BT,
                                                 float* __restrict__ halfmPm) {
  __shared__ float muL[DD];
  __shared__ float red[256];
  const int tid = threadIdx.x;
  const int c = blockIdx.x;
  const int j = blockIdx.y;
  for (int i = tid; i < DD; i += 256) muL[i] = mu[(long)c * DD + i];
  __syncthreads();
  const int col = j * 256 + tid;
  float a = 0.f;
  for (int d = 0; d < DD; ++d) a += muL[d] * P[(long)d * DD + col];
  BT[(long)(DD + c) * DD + col] = __float2bfloat16(a);
  red[tid] = a * muL[col];
  __syncthreads();
  for (int s = 128; s > 0; s >>= 1) {
    if (tid < s) red[tid] += red[tid + s];
    __syncthreads();
  }
  if (tid == 0) atomicAdd(&halfmPm[c], 0.5f * red[0]);
}

// ---------------- GEMM core (R1-verified 128x128 tile, BK=64, 4 waves) ----------------
// + T3 minimum-2-phase prefetch: double-buffered LDS, STAGE(t+1) issued before COMPUTE(t),
// one __syncthreads per K-step (its vmcnt(0) drain lands AFTER compute overlapped the latency).

#define STAGE(As_, Bs_, kt_)                                                            \
  do {                                                                                  \
    _Pragma("unroll")                                                                   \
    for (int i = 0; i < 4; ++i) {                                                       \
      const int rr = i * 32 + w * 8;                                                    \
      const bf16* gA = A + (rowA0 + rr + sr) * (long)LDK + (kt_) + sc;                  \
      const bf16* gB = B + (rowB0 + rr + sr) * (long)LDK + (kt_) + sc;                  \
      __builtin_amdgcn_global_load_lds(                                                 \
          (const __attribute__((address_space(1))) unsigned int*)gA,                    \
          (__attribute__((address_space(3))) unsigned int*)((As_) + rr * 64), 16, 0, 0);\
      __builtin_amdgcn_global_load_lds(                                                 \
          (const __attribute__((address_space(1))) unsigned int*)gB,                    \
          (__attribute__((address_space(3))) unsigned int*)((Bs_) + rr * 64), 16, 0, 0);\
    }                                                                                   \
  } while (0)

#define COMPUTE(As_, Bs_)                                                               \
  do {                                                                                  \
    _Pragma("unroll")                                                                   \
    for (int kk = 0; kk < 64; kk += 32) {                                               \
      bf16x8 av[4], bv[4];                                                              \
      _Pragma("unroll")                                                                 \
      for (int m = 0; m < 4; ++m)                                                       \
        av[m] = *(const bf16x8*)((As_) + (wr * 64 + m * 16 + fr) * 64 + kk + fq * 8);   \
      _Pragma("unroll")                                                                 \
      for (int n = 0; n < 4; ++n)                                                       \
        bv[n] = *(const bf16x8*)((Bs_) + (wc * 64 + n * 16 + fr) * 64 + kk + fq * 8);   \
      _Pragma("unroll")                                                                 \
      for (int m = 0; m < 4; ++m)                                                       \
        _Pragma("unroll")                                                               \
        for (int n = 0; n < 4; ++n)                                                     \
          acc[m][n] = __builtin_amdgcn_mfma_f32_16x16x32_bf16(av[m], bv[n],             \
                                                              acc[m][n], 0, 0, 0);      \
    }                                                                                   \
  } while (0)

template<int LDK>
__device__ __forceinline__ void gemm_mainloop_pf(
    const bf16* __restrict__ A, const bf16* __restrict__ B,
    long rowA0, long rowB0,
    bf16* As0, bf16* Bs0, bf16* As1, bf16* Bs1, f32x4 acc[4][4])
{
  const int tid  = threadIdx.x;
  const int lane = tid & 63;
  const int w    = tid >> 6;            // 0..3
  const int wr = w >> 1, wc = w & 1;
  const int fr = lane & 15, fq = lane >> 4;
  const int sr = lane >> 3;             // staging row within 8-row chunk
  const int sc = (lane & 7) * 8;        // staging col offset (8 bf16 = 16B)

  STAGE(As0, Bs0, 0);
  // LDK is a multiple of 128 -> even number of 64-wide K-steps, statically double-buffered.
#pragma unroll 1
  for (int kt = 0; kt < LDK; kt += 128) {
    __syncthreads();                          // buf0 staged (vmcnt drained) + all waves synced
    if (kt + 64 < LDK) STAGE(As1, Bs1, kt + 64);
    COMPUTE(As0, Bs0);
    __syncthreads();                          // buf1 staged + reads of buf0 done everywhere
    if (kt + 128 < LDK) STAGE(As0, Bs0, kt + 128);
    COMPUTE(As1, Bs1);
  }
}

// GEMM1: zb = xb @ Wt^T   [8192,2048]x[768,2048]^T -> bf16 [8192,768]
__global__ __launch_bounds__(256, 2) void k_gemm1(const bf16* __restrict__ xb,
                                                  const bf16* __restrict__ Wt,
                                                  bf16* __restrict__ zb) {
  __shared__ __align__(16) bf16 As0[128 * 64], Bs0[128 * 64];
  __shared__ __align__(16) bf16 As1[128 * 64], Bs1[128 * 64];
  f32x4 acc[4][4];
#pragma unroll
  for (int m = 0; m < 4; ++m)
#pragma unroll
    for (int n = 0; n < 4; ++n) acc[m][n] = (f32x4){0.f, 0.f, 0.f, 0.f};
  const long bm = blockIdx.y, bn = blockIdx.x;
  gemm_mainloop_pf<DIN>(xb, Wt, bm * 128, bn * 128, As0, Bs0, As1, Bs1, acc);
  const int tid = threadIdx.x, lane = tid & 63, w = tid >> 6;
  const int wr = w >> 1, wc = w & 1, fr = lane & 15, fq = lane >> 4;
#pragma unroll
  for (int m = 0; m < 4; ++m)
#pragma unroll
    for (int n = 0; n < 4; ++n)
#pragma unroll
      for (int j = 0; j < 4; ++j) {
        long row = bm * 128 + wr * 64 + m * 16 + fq * 4 + j;
        long col = bn * 128 + wc * 64 + n * 16 + fr;
        zb[row * DD + col] = __float2bfloat16(acc[m][n][j]);
      }
}

// GEMM2: out2 = zb @ BT^T, BT = [P | muP | 0] as [896,768].
// bn<6: zP tile -> rowdot with zb -> atomicAdd zPz[row]
// bn==6: score tile -> max_c(s - halfmPm[c]) -> smax[row]
__global__ __launch_bounds__(256, 2) void k_gemm2(const bf16* __restrict__ zb,
                                                  const bf16* __restrict__ BT,
                                                  const float* __restrict__ halfmPm,
                                                  float* __restrict__ zPz,
                                                  float* __restrict__ smax) {
  __shared__ __align__(16) bf16 As0[128 * 64], Bs0[128 * 64];
  __shared__ __align__(16) bf16 As1[128 * 64], Bs1[128 * 64];
  __shared__ float sred[2][128];
  f32x4 acc[4][4];
#pragma unroll
  for (int m = 0; m < 4; ++m)
#pragma unroll
    for (int n = 0; n < 4; ++n) acc[m][n] = (f32x4){0.f, 0.f, 0.f, 0.f};
  const long bm = blockIdx.y, bn = blockIdx.x;
  // DD=768 = 6*128 -> even K-steps, OK for the 2x-unrolled loop
  gemm_mainloop_pf<DD>(zb, BT, bm * 128, bn * 128, As0, Bs0, As1, Bs1, acc);
  const int tid = threadIdx.x, lane = tid & 63, w = tid >> 6;
  const int wr = w >> 1, wc = w & 1, fr = lane & 15, fq = lane >> 4;

  if (bn < 6) {
    float p[4][4];
#pragma unroll
    for (int m = 0; m < 4; ++m)
#pragma unroll
      for (int j = 0; j < 4; ++j) p[m][j] = 0.f;
#pragma unroll
    for (int m = 0; m < 4; ++m)
#pragma unroll
      for (int n = 0; n < 4; ++n)
#pragma unroll
        for (int j = 0; j < 4; ++j) {
          long row = bm * 128 + wr * 64 + m * 16 + fq * 4 + j;
          long col = bn * 128 + wc * 64 + n * 16 + fr;
          p[m][j] += acc[m][n][j] * __bfloat162float(zb[row * DD + col]);
        }
#pragma unroll
    for (int m = 0; m < 4; ++m)
#pragma unroll
      for (int j = 0; j < 4; ++j) {
        float v = p[m][j];
        v += __shfl_xor(v, 1, 64);
        v += __shfl_xor(v, 2, 64);
        v += __shfl_xor(v, 4, 64);
        v += __shfl_xor(v, 8, 64);
        if (fr == 0)
          atomicAdd(&zPz[bm * 128 + wr * 64 + m * 16 + fq * 4 + j], v);
      }
  } else {
    float hm[4];
#pragma unroll
    for (int n = 0; n < 4; ++n) hm[n] = halfmPm[wc * 64 + n * 16 + fr];
    float mx[4][4];
#pragma unroll
    for (int m = 0; m < 4; ++m)
#pragma unroll
      for (int j = 0; j < 4; ++j) mx[m][j] = -3e38f;
#pragma unroll
    for (int m = 0; m < 4; ++m)
#pragma unroll
      for (int n = 0; n < 4; ++n)
#pragma unroll
        for (int j = 0; j < 4; ++j)
          mx[m][j] = fmaxf(mx[m][j], acc[m][n][j] - hm[n]);
#pragma unroll
    for (int m = 0; m < 4; ++m)
#pragma unroll
      for (int j = 0; j < 4; ++j) {
        float v = mx[m][j];
        v = fmaxf(v, __shfl_xor(v, 1, 64));
        v = fmaxf(v, __shfl_xor(v, 2, 64));
        v = fmaxf(v, __shfl_xor(v, 4, 64));
        v = fmaxf(v, __shfl_xor(v, 8, 64));
        if (fr == 0) sred[wc][wr * 64 + m * 16 + fq * 4 + j] = v;
      }
    __syncthreads();
    if (tid < 128) smax[bm * 128 + tid] = fmaxf(sred[0][tid], sred[1][tid]);
  }
}

__global__ void k_final(const float* __restrict__ smax, const float* __restrict__ zPz,
                        float* __restrict__ out) {
  int i = blockIdx.x * 256 + threadIdx.x;
  if (i < NROWS) out[i] = smax[i] - 0.5f * zPz[i];
}

// ---------------- launch ----------------

extern "C" void kernel_launch(void* const* d_in, const int* in_sizes, int n_in,
                              void* d_out, int out_size, void* d_ws, size_t ws_size,
                              hipStream_t stream) {
  const float* x  = (const float*)d_in[0];
  const float* W  = (const float*)d_in[1];
  const float* mu = (const float*)d_in[2];
  const float* P  = (const float*)d_in[3];
  float* out = (float*)d_out;

  char* ws = (char*)d_ws;
  bf16*  xb   = (bf16*)(ws);                       // 33,554,432
  bf16*  Wt   = (bf16*)(ws + 33554432);            //  3,145,728
  bf16*  BT   = (bf16*)(ws + 36700160);            //  1,376,256
  bf16*  zb   = (bf16*)(ws + 38076416);            // 12,582,912
  float* hm   = (float*)(ws + 50659328);           // 512 B
  float* zPz  = (float*)(ws + 50659840);           // 32,768 B
  float* smax = (float*)(ws + 50692608);           // 32,768 B

  // hm + zPz + smax are contiguous: one memset covers all three
  hipMemsetAsync(ws + 50659328, 0, 66048, stream);
  k_convert_x  <<<8192, 256, 0, stream>>>(x, xb);
  k_transpose_W<<<dim3(24, 64), 256, 0, stream>>>(W, Wt);
  k_convert_P  <<<2688, 256, 0, stream>>>(P, BT, hm);
  k_prep_mu    <<<dim3(CCLS, 3), 256, 0, stream>>>(mu, P, BT, hm);
  k_gemm1      <<<dim3(6, 64), 256, 0, stream>>>(xb, Wt, zb);
  k_gemm2      <<<dim3(7, 64), 256, 0, stream>>>(zb, BT, hm, zPz, smax);
  k_final      <<<32, 256, 0, stream>>>(smax, zPz, out);
}

// Round 5
// 119.324 us; speedup vs baseline: 1.5413x; 1.0565x over previous
//
#include <hip/hip_runtime.h>
#include <hip/hip_bf16.h>

typedef __attribute__((ext_vector_type(8))) short bf16x8;
typedef __attribute__((ext_vector_type(4))) float f32x4;
typedef __hip_bfloat16 bf16;

#define NROWS 8192
#define DIN   2048
#define DD    768
#define CCLS  100

// ---------------- prep kernels ----------------

// x f32 -> bf16, 8 elems/thread
__global__ void k_convert_x(const float* __restrict__ x, bf16* __restrict__ xb) {
  long i = ((long)blockIdx.x * 256 + threadIdx.x) * 8;
  float4 v0 = *(const float4*)(x + i);
  float4 v1 = *(const float4*)(x + i + 4);
  union { bf16 h[8]; bf16x8 v; } t;
  t.h[0] = __float2bfloat16(v0.x); t.h[1] = __float2bfloat16(v0.y);
  t.h[2] = __float2bfloat16(v0.z); t.h[3] = __float2bfloat16(v0.w);
  t.h[4] = __float2bfloat16(v1.x); t.h[5] = __float2bfloat16(v1.y);
  t.h[6] = __float2bfloat16(v1.z); t.h[7] = __float2bfloat16(v1.w);
  *(bf16x8*)(xb + i) = t.v;
}

// W [2048,768] f32 -> Wt [768,2048] bf16 (tiled transpose)
__global__ void k_transpose_W(const float* __restrict__ W, bf16* __restrict__ Wt) {
  __shared__ float tile[32][33];
  int tx = threadIdx.x & 31;
  int ty = threadIdx.x >> 5;          // 0..7
  int n0 = blockIdx.x * 32;
  int k0 = blockIdx.y * 32;
#pragma unroll
  for (int i = 0; i < 4; ++i)
    tile[ty + 8*i][tx] = W[(long)(k0 + ty + 8*i) * DD + n0 + tx];
  __syncthreads();
#pragma unroll
  for (int i = 0; i < 4; ++i)
    Wt[(long)(n0 + ty + 8*i) * DIN + k0 + tx] = __float2bfloat16(tile[tx][ty + 8*i]);
}

// P f32 -> BT rows [0,768); zero pad rows [868,896); hm pads [100,128) = +1e30
__global__ void k_convert_P(const float* __restrict__ P, bf16* __restrict__ BT,
                            float* __restrict__ halfmPm) {
  int id = blockIdx.x * 256 + threadIdx.x;     // 0 .. 896*768-1
  int r = id / DD;
  if (r < DD)                BT[id] = __float2bfloat16(P[id]);
  else if (r >= DD + CCLS)   BT[id] = __float2bfloat16(0.f);
  if (id >= CCLS && id < 128) halfmPm[id] = 1e30f;
}

// block (c, j): cols [j*256, j*256+256) of muP[c] = mu[c] @ P; partial 0.5*mu.muP -> atomicAdd hm[c]
__global__ __launch_bounds__(256) void k_prep_mu(const float* __restrict__ mu,
                                                 const float* __restrict__ P,
                                                 bf16* __restrict__ BT,
                                                 float* __restrict__ halfmPm) {
  __shared__ float muL[DD];
  __shared__ float red[256];
  const int tid = threadIdx.x;
  const int c = blockIdx.x;
  const int j = blockIdx.y;
  for (int i = tid; i < DD; i += 256) muL[i] = mu[(long)c * DD + i];
  __syncthreads();
  const int col = j * 256 + tid;
  float a = 0.f;
  for (int d = 0; d < DD; ++d) a += muL[d] * P[(long)d * DD + col];
  BT[(long)(DD + c) * DD + col] = __float2bfloat16(a);
  red[tid] = a * muL[col];
  __syncthreads();
  for (int s = 128; s > 0; s >>= 1) {
    if (tid < s) red[tid] += red[tid + s];
    __syncthreads();
  }
  if (tid == 0) atomicAdd(&halfmPm[c], 0.5f * red[0]);
}

// ---------------- GEMM core (R4: 128x128 tile, BK=64, 4 waves, 2-phase dbuf) ----------
// R5 change: T1 bijective XCD swizzle on a flat grid (nwg%8==0), so the bn-blocks
// sharing one A-panel land on the SAME XCD's L2 instead of 6 different ones.

#define STAGE(As_, Bs_, kt_)                                                            \
  do {                                                                                  \
    _Pragma("unroll")                                                                   \
    for (int i = 0; i < 4; ++i) {                                                       \
      const int rr = i * 32 + w * 8;                                                    \
      const bf16* gA = A + (rowA0 + rr + sr) * (long)LDK + (kt_) + sc;                  \
      const bf16* gB = B + (rowB0 + rr + sr) * (long)LDK + (kt_) + sc;                  \
      __builtin_amdgcn_global_load_lds(                                                 \
          (const __attribute__((address_space(1))) unsigned int*)gA,                    \
          (__attribute__((address_space(3))) unsigned int*)((As_) + rr * 64), 16, 0, 0);\
      __builtin_amdgcn_global_load_lds(                                                 \
          (const __attribute__((address_space(1))) unsigned int*)gB,                    \
          (__attribute__((address_space(3))) unsigned int*)((Bs_) + rr * 64), 16, 0, 0);\
    }                                                                                   \
  } while (0)

#define COMPUTE(As_, Bs_)                                                               \
  do {                                                                                  \
    _Pragma("unroll")                                                                   \
    for (int kk = 0; kk < 64; kk += 32) {                                               \
      bf16x8 av[4], bv[4];                                                              \
      _Pragma("unroll")                                                                 \
      for (int m = 0; m < 4; ++m)                                                       \
        av[m] = *(const bf16x8*)((As_) + (wr * 64 + m * 16 + fr) * 64 + kk + fq * 8);   \
      _Pragma("unroll")                                                                 \
      for (int n = 0; n < 4; ++n)                                                       \
        bv[n] = *(const bf16x8*)((Bs_) + (wc * 64 + n * 16 + fr) * 64 + kk + fq * 8);   \
      _Pragma("unroll")                                                                 \
      for (int m = 0; m < 4; ++m)                                                       \
        _Pragma("unroll")                                                               \
        for (int n = 0; n < 4; ++n)                                                     \
          acc[m][n] = __builtin_amdgcn_mfma_f32_16x16x32_bf16(av[m], bv[n],             \
                                                              acc[m][n], 0, 0, 0);      \
    }                                                                                   \
  } while (0)

template<int LDK>
__device__ __forceinline__ void gemm_mainloop_pf(
    const bf16* __restrict__ A, const bf16* __restrict__ B,
    long rowA0, long rowB0,
    bf16* As0, bf16* Bs0, bf16* As1, bf16* Bs1, f32x4 acc[4][4])
{
  const int tid  = threadIdx.x;
  const int lane = tid & 63;
  const int w    = tid >> 6;            // 0..3
  const int wr = w >> 1, wc = w & 1;
  const int fr = lane & 15, fq = lane >> 4;
  const int sr = lane >> 3;             // staging row within 8-row chunk
  const int sc = (lane & 7) * 8;        // staging col offset (8 bf16 = 16B)

  STAGE(As0, Bs0, 0);
#pragma unroll 1
  for (int kt = 0; kt < LDK; kt += 128) {
    __syncthreads();                          // buf0 staged + all waves synced
    if (kt + 64 < LDK) STAGE(As1, Bs1, kt + 64);
    COMPUTE(As0, Bs0);
    __syncthreads();                          // buf1 staged + reads of buf0 done
    if (kt + 128 < LDK) STAGE(As0, Bs0, kt + 128);
    COMPUTE(As1, Bs1);
  }
}

// GEMM1: zb = xb @ Wt^T   [8192,2048]x[768,2048]^T -> bf16 [8192,768]
// flat grid 384, XCD swizzle: each XCD owns 48 blocks = 8 bm-panels x 6 bn.
__global__ __launch_bounds__(256, 2) void k_gemm1(const bf16* __restrict__ xb,
                                                  const bf16* __restrict__ Wt,
                                                  bf16* __restrict__ zb) {
  __shared__ __align__(16) bf16 As0[128 * 64], Bs0[128 * 64];
  __shared__ __align__(16) bf16 As1[128 * 64], Bs1[128 * 64];
  f32x4 acc[4][4];
#pragma unroll
  for (int m = 0; m < 4; ++m)
#pragma unroll
    for (int n = 0; n < 4; ++n) acc[m][n] = (f32x4){0.f, 0.f, 0.f, 0.f};
  const int bid = blockIdx.x;                 // 0..383
  const int s = (bid & 7) * 48 + (bid >> 3);  // bijective: 384 % 8 == 0
  const long bm = s / 6, bn = s % 6;
  gemm_mainloop_pf<DIN>(xb, Wt, bm * 128, bn * 128, As0, Bs0, As1, Bs1, acc);
  const int tid = threadIdx.x, lane = tid & 63, w = tid >> 6;
  const int wr = w >> 1, wc = w & 1, fr = lane & 15, fq = lane >> 4;
#pragma unroll
  for (int m = 0; m < 4; ++m)
#pragma unroll
    for (int n = 0; n < 4; ++n)
#pragma unroll
      for (int j = 0; j < 4; ++j) {
        long row = bm * 128 + wr * 64 + m * 16 + fq * 4 + j;
        long col = bn * 128 + wc * 64 + n * 16 + fr;
        zb[row * DD + col] = __float2bfloat16(acc[m][n][j]);
      }
}

// GEMM2: out2 = zb @ BT^T, BT = [P | muP | 0] as [896,768].
// flat grid 448, XCD swizzle: each XCD owns 56 blocks = 8 bm-panels x 7 bn.
// bn<6: zP tile -> rowdot with zb -> atomicAdd zPz[row]
// bn==6: score tile -> max_c(s - halfmPm[c]) -> smax[row]
__global__ __launch_bounds__(256, 2) void k_gemm2(const bf16* __restrict__ zb,
                                                  const bf16* __restrict__ BT,
                                                  const float* __restrict__ halfmPm,
                                                  float* __restrict__ zPz,
                                                  float* __restrict__ smax) {
  __shared__ __align__(16) bf16 As0[128 * 64], Bs0[128 * 64];
  __shared__ __align__(16) bf16 As1[128 * 64], Bs1[128 * 64];
  __shared__ float sred[2][128];
  f32x4 acc[4][4];
#pragma unroll
  for (int m = 0; m < 4; ++m)
#pragma unroll
    for (int n = 0; n < 4; ++n) acc[m][n] = (f32x4){0.f, 0.f, 0.f, 0.f};
  const int bid = blockIdx.x;                 // 0..447
  const int s = (bid & 7) * 56 + (bid >> 3);  // bijective: 448 % 8 == 0
  const long bm = s / 7, bn = s % 7;
  gemm_mainloop_pf<DD>(zb, BT, bm * 128, bn * 128, As0, Bs0, As1, Bs1, acc);
  const int tid = threadIdx.x, lane = tid & 63, w = tid >> 6;
  const int wr = w >> 1, wc = w & 1, fr = lane & 15, fq = lane >> 4;

  if (bn < 6) {
    float p[4][4];
#pragma unroll
    for (int m = 0; m < 4; ++m)
#pragma unroll
      for (int j = 0; j < 4; ++j) p[m][j] = 0.f;
#pragma unroll
    for (int m = 0; m < 4; ++m)
#pragma unroll
      for (int n = 0; n < 4; ++n)
#pragma unroll
        for (int j = 0; j < 4; ++j) {
          long row = bm * 128 + wr * 64 + m * 16 + fq * 4 + j;
          long col = bn * 128 + wc * 64 + n * 16 + fr;
          p[m][j] += acc[m][n][j] * __bfloat162float(zb[row * DD + col]);
        }
#pragma unroll
    for (int m = 0; m < 4; ++m)
#pragma unroll
      for (int j = 0; j < 4; ++j) {
        float v = p[m][j];
        v += __shfl_xor(v, 1, 64);
        v += __shfl_xor(v, 2, 64);
        v += __shfl_xor(v, 4, 64);
        v += __shfl_xor(v, 8, 64);
        if (fr == 0)
          atomicAdd(&zPz[bm * 128 + wr * 64 + m * 16 + fq * 4 + j], v);
      }
  } else {
    float hm[4];
#pragma unroll
    for (int n = 0; n < 4; ++n) hm[n] = halfmPm[wc * 64 + n * 16 + fr];
    float mx[4][4];
#pragma unroll
    for (int m = 0; m < 4; ++m)
#pragma unroll
      for (int j = 0; j < 4; ++j) mx[m][j] = -3e38f;
#pragma unroll
    for (int m = 0; m < 4; ++m)
#pragma unroll
      for (int n = 0; n < 4; ++n)
#pragma unroll
        for (int j = 0; j < 4; ++j)
          mx[m][j] = fmaxf(mx[m][j], acc[m][n][j] - hm[n]);
#pragma unroll
    for (int m = 0; m < 4; ++m)
#pragma unroll
      for (int j = 0; j < 4; ++j) {
        float v = mx[m][j];
        v = fmaxf(v, __shfl_xor(v, 1, 64));
        v = fmaxf(v, __shfl_xor(v, 2, 64));
        v = fmaxf(v, __shfl_xor(v, 4, 64));
        v = fmaxf(v, __shfl_xor(v, 8, 64));
        if (fr == 0) sred[wc][wr * 64 + m * 16 + fq * 4 + j] = v;
      }
    __syncthreads();
    if (tid < 128) smax[bm * 128 + tid] = fmaxf(sred[0][tid], sred[1][tid]);
  }
}

__global__ void k_final(const float* __restrict__ smax, const float* __restrict__ zPz,
                        float* __restrict__ out) {
  int i = blockIdx.x * 256 + threadIdx.x;
  if (i < NROWS) out[i] = smax[i] - 0.5f * zPz[i];
}

// ---------------- launch ----------------

extern "C" void kernel_launch(void* const* d_in, const int* in_sizes, int n_in,
                              void* d_out, int out_size, void* d_ws, size_t ws_size,
                              hipStream_t stream) {
  const float* x  = (const float*)d_in[0];
  const float* W  = (const float*)d_in[1];
  const float* mu = (const float*)d_in[2];
  const float* P  = (const float*)d_in[3];
  float* out = (float*)d_out;

  char* ws = (char*)d_ws;
  bf16*  xb   = (bf16*)(ws);                       // 33,554,432
  bf16*  Wt   = (bf16*)(ws + 33554432);            //  3,145,728
  bf16*  BT   = (bf16*)(ws + 36700160);            //  1,376,256
  bf16*  zb   = (bf16*)(ws + 38076416);            // 12,582,912
  float* hm   = (float*)(ws + 50659328);           // 512 B
  float* zPz  = (float*)(ws + 50659840);           // 32,768 B
  float* smax = (float*)(ws + 50692608);           // 32,768 B

  // hm + zPz + smax are contiguous: one memset covers all three
  hipMemsetAsync(ws + 50659328, 0, 66048, stream);
  k_convert_x  <<<8192, 256, 0, stream>>>(x, xb);
  k_transpose_W<<<dim3(24, 64), 256, 0, stream>>>(W, Wt);
  k_convert_P  <<<2688, 256, 0, stream>>>(P, BT, hm);
  k_prep_mu    <<<dim3(CCLS, 3), 256, 0, stream>>>(mu, P, BT, hm);
  k_gemm1      <<<384, 256, 0, stream>>>(xb, Wt, zb);
  k_gemm2      <<<448, 256, 0, stream>>>(zb, BT, hm, zPz, smax);
  k_final      <<<32, 256, 0, stream>>>(smax, zPz, out);
}

// Round 6
// 106.953 us; speedup vs baseline: 1.7195x; 1.1157x over previous
//
#include <hip/hip_runtime.h>
#include <hip/hip_bf16.h>

typedef __attribute__((ext_vector_type(8))) short bf16x8;
typedef __attribute__((ext_vector_type(4))) float f32x4;
typedef __hip_bfloat16 bf16;

#define NROWS 8192
#define DIN   2048
#define DD    768
#define CCLS  100

// ---------------- prep kernels ----------------

// x f32 -> bf16, 8 elems/thread
__global__ void k_convert_x(const float* __restrict__ x, bf16* __restrict__ xb) {
  long i = ((long)blockIdx.x * 256 + threadIdx.x) * 8;
  float4 v0 = *(const float4*)(x + i);
  float4 v1 = *(const float4*)(x + i + 4);
  union { bf16 h[8]; bf16x8 v; } t;
  t.h[0] = __float2bfloat16(v0.x); t.h[1] = __float2bfloat16(v0.y);
  t.h[2] = __float2bfloat16(v0.z); t.h[3] = __float2bfloat16(v0.w);
  t.h[4] = __float2bfloat16(v1.x); t.h[5] = __float2bfloat16(v1.y);
  t.h[6] = __float2bfloat16(v1.z); t.h[7] = __float2bfloat16(v1.w);
  *(bf16x8*)(xb + i) = t.v;
}

// W [2048,768] f32 -> Wt [768,2048] bf16 (tiled transpose)
__global__ void k_transpose_W(const float* __restrict__ W, bf16* __restrict__ Wt) {
  __shared__ float tile[32][33];
  int tx = threadIdx.x & 31;
  int ty = threadIdx.x >> 5;          // 0..7
  int n0 = blockIdx.x * 32;
  int k0 = blockIdx.y * 32;
#pragma unroll
  for (int i = 0; i < 4; ++i)
    tile[ty + 8*i][tx] = W[(long)(k0 + ty + 8*i) * DD + n0 + tx];
  __syncthreads();
#pragma unroll
  for (int i = 0; i < 4; ++i)
    Wt[(long)(n0 + ty + 8*i) * DIN + k0 + tx] = __float2bfloat16(tile[tx][ty + 8*i]);
}

// P f32 -> BT rows [0,768); zero pad rows [868,896); hm pads [100,128) = +1e30
__global__ void k_convert_P(const float* __restrict__ P, bf16* __restrict__ BT,
                            float* __restrict__ halfmPm) {
  int id = blockIdx.x * 256 + threadIdx.x;     // 0 .. 896*768-1
  int r = id / DD;
  if (r < DD)                BT[id] = __float2bfloat16(P[id]);
  else if (r >= DD + CCLS)   BT[id] = __float2bfloat16(0.f);
  if (id >= CCLS && id < 128) halfmPm[id] = 1e30f;
}

// block (c, j): cols [j*256, j*256+256) of muP[c] = mu[c] @ P; partial 0.5*mu.muP -> atomicAdd hm[c]
__global__ __launch_bounds__(256) void k_prep_mu(const float* __restrict__ mu,
                                                 const float* __restrict__ P,
                                                 bf16* __restrict__ BT,
                                                 float* __restrict__ halfmPm) {
  __shared__ float muL[DD];
  __shared__ float red[256];
  const int tid = threadIdx.x;
  const int c = blockIdx.x;
  const int j = blockIdx.y;
  for (int i = tid; i < DD; i += 256) muL[i] = mu[(long)c * DD + i];
  __syncthreads();
  const int col = j * 256 + tid;
  float a = 0.f;
  for (int d = 0; d < DD; ++d) a += muL[d] * P[(long)d * DD + col];
  BT[(long)(DD + c) * DD + col] = __float2bfloat16(a);
  red[tid] = a * muL[col];
  __syncthreads();
  for (int s = 128; s > 0; s >>= 1) {
    if (tid < s) red[tid] += red[tid + s];
    __syncthreads();
  }
  if (tid == 0) atomicAdd(&halfmPm[c], 0.5f * red[0]);
}

// ---------------- GEMM core (128x128 tile, BK=64, 4 waves, 2-phase dbuf, T1 swizzle) ----
// R6 change: T2 XOR bank-swizzle, both-sides-or-neither (rule #21):
//   LDS dest stays LINEAR (global_load_lds requires it); the 16B slot-permutation is
//   applied to the per-lane GLOBAL source column (sc: slot s -> s^sr within each 8-row
//   stripe), so LDS[row][s] = G[row][s^(row&7)]. Reads apply the same XOR.
//   Read invariant: row&7 == fr&7 for every fragment row (all row bases are mult of 8),
//   so the swizzled slot = fq ^ (kk>>3) ^ (fr&7) -- loop-invariant per lane, zero extra
//   VALU. Fixes the 16-lane same-bank-group conflict on every ds_read_b128 (9.4M cyc).

#define STAGE(As_, Bs_, kt_)                                                            \
  do {                                                                                  \
    _Pragma("unroll")                                                                   \
    for (int i = 0; i < 4; ++i) {                                                       \
      const int rr = i * 32 + w * 8;                                                    \
      const bf16* gA = A + (rowA0 + rr + sr) * (long)LDK + (kt_) + sc;                  \
      const bf16* gB = B + (rowB0 + rr + sr) * (long)LDK + (kt_) + sc;                  \
      __builtin_amdgcn_global_load_lds(                                                 \
          (const __attribute__((address_space(1))) unsigned int*)gA,                    \
          (__attribute__((address_space(3))) unsigned int*)((As_) + rr * 64), 16, 0, 0);\
      __builtin_amdgcn_global_load_lds(                                                 \
          (const __attribute__((address_space(1))) unsigned int*)gB,                    \
          (__attribute__((address_space(3))) unsigned int*)((Bs_) + rr * 64), 16, 0, 0);\
    }                                                                                   \
  } while (0)

#define COMPUTE(As_, Bs_)                                                               \
  do {                                                                                  \
    _Pragma("unroll")                                                                   \
    for (int kk = 0; kk < 64; kk += 32) {                                               \
      const int slot = (fq ^ (kk >> 3) ^ (fr & 7)) * 8;  /* swizzled 16B slot */        \
      bf16x8 av[4], bv[4];                                                              \
      _Pragma("unroll")                                                                 \
      for (int m = 0; m < 4; ++m)                                                       \
        av[m] = *(const bf16x8*)((As_) + (wr * 64 + m * 16 + fr) * 64 + slot);          \
      _Pragma("unroll")                                                                 \
      for (int n = 0; n < 4; ++n)                                                       \
        bv[n] = *(const bf16x8*)((Bs_) + (wc * 64 + n * 16 + fr) * 64 + slot);          \
      _Pragma("unroll")                                                                 \
      for (int m = 0; m < 4; ++m)                                                       \
        _Pragma("unroll")                                                               \
        for (int n = 0; n < 4; ++n)                                                     \
          acc[m][n] = __builtin_amdgcn_mfma_f32_16x16x32_bf16(av[m], bv[n],             \
                                                              acc[m][n], 0, 0, 0);      \
    }                                                                                   \
  } while (0)

template<int LDK>
__device__ __forceinline__ void gemm_mainloop_pf(
    const bf16* __restrict__ A, const bf16* __restrict__ B,
    long rowA0, long rowB0,
    bf16* As0, bf16* Bs0, bf16* As1, bf16* Bs1, f32x4 acc[4][4])
{
  const int tid  = threadIdx.x;
  const int lane = tid & 63;
  const int w    = tid >> 6;            // 0..3
  const int wr = w >> 1, wc = w & 1;
  const int fr = lane & 15, fq = lane >> 4;
  const int sr = lane >> 3;                      // staging row within 8-row chunk (0..7)
  const int sc = (((lane & 7) ^ sr) * 8);        // inverse-swizzled global 16B slot

  STAGE(As0, Bs0, 0);
#pragma unroll 1
  for (int kt = 0; kt < LDK; kt += 128) {
    __syncthreads();                          // buf0 staged + all waves synced
    if (kt + 64 < LDK) STAGE(As1, Bs1, kt + 64);
    COMPUTE(As0, Bs0);
    __syncthreads();                          // buf1 staged + reads of buf0 done
    if (kt + 128 < LDK) STAGE(As0, Bs0, kt + 128);
    COMPUTE(As1, Bs1);
  }
}

// GEMM1: zb = xb @ Wt^T   [8192,2048]x[768,2048]^T -> bf16 [8192,768]
// flat grid 384, XCD swizzle: each XCD owns 48 blocks = 8 bm-panels x 6 bn.
__global__ __launch_bounds__(256, 2) void k_gemm1(const bf16* __restrict__ xb,
                                                  const bf16* __restrict__ Wt,
                                                  bf16* __restrict__ zb) {
  __shared__ __align__(16) bf16 As0[128 * 64], Bs0[128 * 64];
  __shared__ __align__(16) bf16 As1[128 * 64], Bs1[128 * 64];
  f32x4 acc[4][4];
#pragma unroll
  for (int m = 0; m < 4; ++m)
#pragma unroll
    for (int n = 0; n < 4; ++n) acc[m][n] = (f32x4){0.f, 0.f, 0.f, 0.f};
  const int bid = blockIdx.x;                 // 0..383
  const int s = (bid & 7) * 48 + (bid >> 3);  // bijective: 384 % 8 == 0
  const long bm = s / 6, bn = s % 6;
  gemm_mainloop_pf<DIN>(xb, Wt, bm * 128, bn * 128, As0, Bs0, As1, Bs1, acc);
  const int tid = threadIdx.x, lane = tid & 63, w = tid >> 6;
  const int wr = w >> 1, wc = w & 1, fr = lane & 15, fq = lane >> 4;
#pragma unroll
  for (int m = 0; m < 4; ++m)
#pragma unroll
    for (int n = 0; n < 4; ++n)
#pragma unroll
      for (int j = 0; j < 4; ++j) {
        long row = bm * 128 + wr * 64 + m * 16 + fq * 4 + j;
        long col = bn * 128 + wc * 64 + n * 16 + fr;
        zb[row * DD + col] = __float2bfloat16(acc[m][n][j]);
      }
}

// GEMM2: out2 = zb @ BT^T, BT = [P | muP | 0] as [896,768].
// flat grid 448, XCD swizzle: each XCD owns 56 blocks = 8 bm-panels x 7 bn.
// bn<6: zP tile -> rowdot with zb -> atomicAdd zPz[row]
// bn==6: score tile -> max_c(s - halfmPm[c]) -> smax[row]
__global__ __launch_bounds__(256, 2) void k_gemm2(const bf16* __restrict__ zb,
                                                  const bf16* __restrict__ BT,
                                                  const float* __restrict__ halfmPm,
                                                  float* __restrict__ zPz,
                                                  float* __restrict__ smax) {
  __shared__ __align__(16) bf16 As0[128 * 64], Bs0[128 * 64];
  __shared__ __align__(16) bf16 As1[128 * 64], Bs1[128 * 64];
  __shared__ float sred[2][128];
  f32x4 acc[4][4];
#pragma unroll
  for (int m = 0; m < 4; ++m)
#pragma unroll
    for (int n = 0; n < 4; ++n) acc[m][n] = (f32x4){0.f, 0.f, 0.f, 0.f};
  const int bid = blockIdx.x;                 // 0..447
  const int s = (bid & 7) * 56 + (bid >> 3);  // bijective: 448 % 8 == 0
  const long bm = s / 7, bn = s % 7;
  gemm_mainloop_pf<DD>(zb, BT, bm * 128, bn * 128, As0, Bs0, As1, Bs1, acc);
  const int tid = threadIdx.x, lane = tid & 63, w = tid >> 6;
  const int wr = w >> 1, wc = w & 1, fr = lane & 15, fq = lane >> 4;

  if (bn < 6) {
    float p[4][4];
#pragma unroll
    for (int m = 0; m < 4; ++m)
#pragma unroll
      for (int j = 0; j < 4; ++j) p[m][j] = 0.f;
#pragma unroll
    for (int m = 0; m < 4; ++m)
#pragma unroll
      for (int n = 0; n < 4; ++n)
#pragma unroll
        for (int j = 0; j < 4; ++j) {
          long row = bm * 128 + wr * 64 + m * 16 + fq * 4 + j;
          long col = bn * 128 + wc * 64 + n * 16 + fr;
          p[m][j] += acc[m][n][j] * __bfloat162float(zb[row * DD + col]);
        }
#pragma unroll
    for (int m = 0; m < 4; ++m)
#pragma unroll
      for (int j = 0; j < 4; ++j) {
        float v = p[m][j];
        v += __shfl_xor(v, 1, 64);
        v += __shfl_xor(v, 2, 64);
        v += __shfl_xor(v, 4, 64);
        v += __shfl_xor(v, 8, 64);
        if (fr == 0)
          atomicAdd(&zPz[bm * 128 + wr * 64 + m * 16 + fq * 4 + j], v);
      }
  } else {
    float hm[4];
#pragma unroll
    for (int n = 0; n < 4; ++n) hm[n] = halfmPm[wc * 64 + n * 16 + fr];
    float mx[4][4];
#pragma unroll
    for (int m = 0; m < 4; ++m)
#pragma unroll
      for (int j = 0; j < 4; ++j) mx[m][j] = -3e38f;
#pragma unroll
    for (int m = 0; m < 4; ++m)
#pragma unroll
      for (int n = 0; n < 4; ++n)
#pragma unroll
        for (int j = 0; j < 4; ++j)
          mx[m][j] = fmaxf(mx[m][j], acc[m][n][j] - hm[n]);
#pragma unroll
    for (int m = 0; m < 4; ++m)
#pragma unroll
      for (int j = 0; j < 4; ++j) {
        float v = mx[m][j];
        v = fmaxf(v, __shfl_xor(v, 1, 64));
        v = fmaxf(v, __shfl_xor(v, 2, 64));
        v = fmaxf(v, __shfl_xor(v, 4, 64));
        v = fmaxf(v, __shfl_xor(v, 8, 64));
        if (fr == 0) sred[wc][wr * 64 + m * 16 + fq * 4 + j] = v;
      }
    __syncthreads();
    if (tid < 128) smax[bm * 128 + tid] = fmaxf(sred[0][tid], sred[1][tid]);
  }
}

__global__ void k_final(const float* __restrict__ smax, const float* __restrict__ zPz,
                        float* __restrict__ out) {
  int i = blockIdx.x * 256 + threadIdx.x;
  if (i < NROWS) out[i] = smax[i] - 0.5f * zPz[i];
}

// ---------------- launch ----------------

extern "C" void kernel_launch(void* const* d_in, const int* in_sizes, int n_in,
                              void* d_out, int out_size, void* d_ws, size_t ws_size,
                              hipStream_t stream) {
  const float* x  = (const float*)d_in[0];
  const float* W  = (const float*)d_in[1];
  const float* mu = (const float*)d_in[2];
  const float* P  = (const float*)d_in[3];
  float* out = (float*)d_out;

  char* ws = (char*)d_ws;
  bf16*  xb   = (bf16*)(ws);                       // 33,554,432
  bf16*  Wt   = (bf16*)(ws + 33554432);            //  3,145,728
  bf16*  BT   = (bf16*)(ws + 36700160);            //  1,376,256
  bf16*  zb   = (bf16*)(ws + 38076416);            // 12,582,912
  float* hm   = (float*)(ws + 50659328);           // 512 B
  float* zPz  = (float*)(ws + 50659840);           // 32,768 B
  float* smax = (float*)(ws + 50692608);           // 32,768 B

  // hm + zPz + smax are contiguous: one memset covers all three
  hipMemsetAsync(ws + 50659328, 0, 66048, stream);
  k_convert_x  <<<8192, 256, 0, stream>>>(x, xb);
  k_transpose_W<<<dim3(24, 64), 256, 0, stream>>>(W, Wt);
  k_convert_P  <<<2688, 256, 0, stream>>>(P, BT, hm);
  k_prep_mu    <<<dim3(CCLS, 3), 256, 0, stream>>>(mu, P, BT, hm);
  k_gemm1      <<<384, 256, 0, stream>>>(xb, Wt, zb);
  k_gemm2      <<<448, 256, 0, stream>>>(zb, BT, hm, zPz, smax);
  k_final      <<<32, 256, 0, stream>>>(smax, zPz, out);
}

// Round 7
// 102.632 us; speedup vs baseline: 1.7920x; 1.0421x over previous
//
#include <hip/hip_runtime.h>
#include <hip/hip_bf16.h>

typedef __attribute__((ext_vector_type(8))) short bf16x8;
typedef __attribute__((ext_vector_type(4))) float f32x4;
typedef __hip_bfloat16 bf16;

#define NROWS 8192
#define DIN   2048
#define DD    768
#define CCLS  100

// ---------------- prep kernels ----------------

// W [2048,768] f32 -> Wt [768,2048] bf16 (tiled transpose)
__global__ void k_transpose_W(const float* __restrict__ W, bf16* __restrict__ Wt) {
  __shared__ float tile[32][33];
  int tx = threadIdx.x & 31;
  int ty = threadIdx.x >> 5;          // 0..7
  int n0 = blockIdx.x * 32;
  int k0 = blockIdx.y * 32;
#pragma unroll
  for (int i = 0; i < 4; ++i)
    tile[ty + 8*i][tx] = W[(long)(k0 + ty + 8*i) * DD + n0 + tx];
  __syncthreads();
#pragma unroll
  for (int i = 0; i < 4; ++i)
    Wt[(long)(n0 + ty + 8*i) * DIN + k0 + tx] = __float2bfloat16(tile[tx][ty + 8*i]);
}

// P f32 -> BT rows [0,768); zero pad rows [868,896); hm pads [100,128) = +1e30
__global__ void k_convert_P(const float* __restrict__ P, bf16* __restrict__ BT,
                            float* __restrict__ halfmPm) {
  int id = blockIdx.x * 256 + threadIdx.x;     // 0 .. 896*768-1
  int r = id / DD;
  if (r < DD)                BT[id] = __float2bfloat16(P[id]);
  else if (r >= DD + CCLS)   BT[id] = __float2bfloat16(0.f);
  if (id >= CCLS && id < 128) halfmPm[id] = 1e30f;
}

// block (c, j): cols [j*256, j*256+256) of muP[c] = mu[c] @ P; partial 0.5*mu.muP -> atomicAdd hm[c]
__global__ __launch_bounds__(256) void k_prep_mu(const float* __restrict__ mu,
                                                 const float* __restrict__ P,
                                                 bf16* __restrict__ BT,
                                                 float* __restrict__ halfmPm) {
  __shared__ float muL[DD];
  __shared__ float red[256];
  const int tid = threadIdx.x;
  const int c = blockIdx.x;
  const int j = blockIdx.y;
  for (int i = tid; i < DD; i += 256) muL[i] = mu[(long)c * DD + i];
  __syncthreads();
  const int col = j * 256 + tid;
  float a = 0.f;
  for (int d = 0; d < DD; ++d) a += muL[d] * P[(long)d * DD + col];
  BT[(long)(DD + c) * DD + col] = __float2bfloat16(a);
  red[tid] = a * muL[col];
  __syncthreads();
  for (int s = 128; s > 0; s >>= 1) {
    if (tid < s) red[tid] += red[tid + s];
    __syncthreads();
  }
  if (tid == 0) atomicAdd(&halfmPm[c], 0.5f * red[0]);
}

// 8 f32 -> bf16x8
__device__ __forceinline__ bf16x8 cvt8(const float4 a, const float4 b) {
  union { bf16 h[8]; bf16x8 v; } t;
  t.h[0] = __float2bfloat16(a.x); t.h[1] = __float2bfloat16(a.y);
  t.h[2] = __float2bfloat16(a.z); t.h[3] = __float2bfloat16(a.w);
  t.h[4] = __float2bfloat16(b.x); t.h[5] = __float2bfloat16(b.y);
  t.h[6] = __float2bfloat16(b.z); t.h[7] = __float2bfloat16(b.w);
  return t.v;
}

// ---------------- shared GEMM pieces (128x128 tile, BK=64, 4 waves, T1+T2) ----------
// T2 layout invariant (both-sides-or-neither, rule #21):
//   LDS[row][s'] = G[row][s' ^ (row&7)]   (s' = 16B slot, 8 slots/row)
//   gemm2/B-path: global_load_lds linear dest + inverse-swizzled SOURCE (sc).
//   gemm1/A-path (R7): reg-staged f32->bf16, ds_write DIRECTLY to slot s^ (row&7).
//   Reads: row&7 == fr&7 for every fragment row -> slot' = fq ^ (kk>>3) ^ (fr&7).

#define STAGE(As_, Bs_, kt_)                                                            \
  do {                                                                                  \
    _Pragma("unroll")                                                                   \
    for (int i = 0; i < 4; ++i) {                                                       \
      const int rr = i * 32 + w * 8;                                                    \
      const bf16* gA = A + (rowA0 + rr + sr) * (long)LDK + (kt_) + sc;                  \
      const bf16* gB = B + (rowB0 + rr + sr) * (long)LDK + (kt_) + sc;                  \
      __builtin_amdgcn_global_load_lds(                                                 \
          (const __attribute__((address_space(1))) unsigned int*)gA,                    \
          (__attribute__((address_space(3))) unsigned int*)((As_) + rr * 64), 16, 0, 0);\
      __builtin_amdgcn_global_load_lds(                                                 \
          (const __attribute__((address_space(1))) unsigned int*)gB,                    \
          (__attribute__((address_space(3))) unsigned int*)((Bs_) + rr * 64), 16, 0, 0);\
    }                                                                                   \
  } while (0)

#define COMPUTE(As_, Bs_)                                                               \
  do {                                                                                  \
    _Pragma("unroll")                                                                   \
    for (int kk = 0; kk < 64; kk += 32) {                                               \
      const int slot = (fq ^ (kk >> 3) ^ (fr & 7)) * 8;  /* swizzled 16B slot */        \
      bf16x8 av[4], bv[4];                                                              \
      _Pragma("unroll")                                                                 \
      for (int m = 0; m < 4; ++m)                                                       \
        av[m] = *(const bf16x8*)((As_) + (wr * 64 + m * 16 + fr) * 64 + slot);          \
      _Pragma("unroll")                                                                 \
      for (int n = 0; n < 4; ++n)                                                       \
        bv[n] = *(const bf16x8*)((Bs_) + (wc * 64 + n * 16 + fr) * 64 + slot);          \
      _Pragma("unroll")                                                                 \
      for (int m = 0; m < 4; ++m)                                                       \
        _Pragma("unroll")                                                               \
        for (int n = 0; n < 4; ++n)                                                     \
          acc[m][n] = __builtin_amdgcn_mfma_f32_16x16x32_bf16(av[m], bv[n],             \
                                                              acc[m][n], 0, 0, 0);      \
    }                                                                                   \
  } while (0)

template<int LDK>
__device__ __forceinline__ void gemm_mainloop_pf(
    const bf16* __restrict__ A, const bf16* __restrict__ B,
    long rowA0, long rowB0,
    bf16* As0, bf16* Bs0, bf16* As1, bf16* Bs1, f32x4 acc[4][4])
{
  const int tid  = threadIdx.x;
  const int lane = tid & 63;
  const int w    = tid >> 6;            // 0..3
  const int wr = w >> 1, wc = w & 1;
  const int fr = lane & 15, fq = lane >> 4;
  const int sr = lane >> 3;                      // staging row within 8-row chunk (0..7)
  const int sc = (((lane & 7) ^ sr) * 8);        // inverse-swizzled global 16B slot

  STAGE(As0, Bs0, 0);
#pragma unroll 1
  for (int kt = 0; kt < LDK; kt += 128) {
    __syncthreads();                          // buf0 staged + all waves synced
    if (kt + 64 < LDK) STAGE(As1, Bs1, kt + 64);
    COMPUTE(As0, Bs0);
    __syncthreads();                          // buf1 staged + reads of buf0 done
    if (kt + 128 < LDK) STAGE(As0, Bs0, kt + 128);
    COMPUTE(As1, Bs1);
  }
}

// GEMM1 (R7): zb = x @ Wt^T, x read as f32 and converted to bf16 IN-KERNEL.
// A path: T14 split -- issue f32 loads for tile t+1 before COMPUTE(t) (latency hides
// under MFMAs), convert+ds_write after COMPUTE, barrier makes them visible.
// flat grid 384, XCD swizzle: each XCD owns 48 blocks = 8 bm-panels x 6 bn.
__global__ __launch_bounds__(256, 2) void k_gemm1(const float* __restrict__ X,
                                                  const bf16* __restrict__ Wt,
                                                  bf16* __restrict__ zb) {
  __shared__ __align__(16) bf16 As0[128 * 64], Bs0[128 * 64];
  __shared__ __align__(16) bf16 As1[128 * 64], Bs1[128 * 64];
  f32x4 acc[4][4];
#pragma unroll
  for (int m = 0; m < 4; ++m)
#pragma unroll
    for (int n = 0; n < 4; ++n) acc[m][n] = (f32x4){0.f, 0.f, 0.f, 0.f};
  const int bid = blockIdx.x;                 // 0..383
  const int s = (bid & 7) * 48 + (bid >> 3);  // bijective: 384 % 8 == 0
  const long bm = s / 6, bn = s % 6;
  const long rowA0 = bm * 128, rowB0 = bn * 128;

  const int tid = threadIdx.x, lane = tid & 63, w = tid >> 6;
  const int wr = w >> 1, wc = w & 1, fr = lane & 15, fq = lane >> 4;
  const int sr = lane >> 3;
  const int sc = (((lane & 7) ^ sr) * 8);     // B staging: inverse-swizzled source slot
  const int asG = tid & 7;                    // A: global 8-float slot (32B)
  const int ar0 = tid >> 3;                   // A: base row 0..31 (rows ar0+32i)
  const int aswz = (asG ^ (ar0 & 7)) * 8;     // A: swizzled LDS slot ((32i) & 7 == 0)

  float4 a0[4], a1[4];                        // in-flight A tile (f32), 32 VGPRs

#define A_LOAD(kt_)                                                          \
  do { _Pragma("unroll")                                                     \
    for (int i = 0; i < 4; ++i) {                                            \
      const float* g = X + (rowA0 + ar0 + i * 32) * (long)DIN + (kt_) + asG * 8; \
      a0[i] = *(const float4*)g;                                             \
      a1[i] = *(const float4*)(g + 4);                                       \
    } } while (0)

#define A_WRITE(As_)                                                         \
  do { _Pragma("unroll")                                                     \
    for (int i = 0; i < 4; ++i)                                              \
      *(bf16x8*)((As_) + (ar0 + i * 32) * 64 + aswz) = cvt8(a0[i], a1[i]);   \
  } while (0)

#define B_STAGE(Bs_, kt_)                                                    \
  do { _Pragma("unroll")                                                     \
    for (int i = 0; i < 4; ++i) {                                            \
      const int rr = i * 32 + w * 8;                                         \
      const bf16* gB = Wt + (rowB0 + rr + sr) * (long)DIN + (kt_) + sc;      \
      __builtin_amdgcn_global_load_lds(                                      \
          (const __attribute__((address_space(1))) unsigned int*)gB,         \
          (__attribute__((address_space(3))) unsigned int*)((Bs_) + rr * 64),\
          16, 0, 0);                                                         \
    } } while (0)

  A_LOAD(0);
  B_STAGE(Bs0, 0);
  A_WRITE(As0);
#pragma unroll 1
  for (int kt = 0; kt < DIN; kt += 128) {
    __syncthreads();                      // As0 writes + Bs0 loads visible to all
    if (kt + 64 < DIN) { A_LOAD(kt + 64); B_STAGE(Bs1, kt + 64); }
    COMPUTE(As0, Bs0);
    if (kt + 64 < DIN) A_WRITE(As1);      // all waves done reading As1 (barrier above)
    __syncthreads();
    if (kt + 128 < DIN) { A_LOAD(kt + 128); B_STAGE(Bs0, kt + 128); }
    COMPUTE(As1, Bs1);
    if (kt + 128 < DIN) A_WRITE(As0);
  }
#undef A_LOAD
#undef A_WRITE
#undef B_STAGE

#pragma unroll
  for (int m = 0; m < 4; ++m)
#pragma unroll
    for (int n = 0; n < 4; ++n)
#pragma unroll
      for (int j = 0; j < 4; ++j) {
        long row = bm * 128 + wr * 64 + m * 16 + fq * 4 + j;
        long col = bn * 128 + wc * 64 + n * 16 + fr;
        zb[row * DD + col] = __float2bfloat16(acc[m][n][j]);
      }
}

// GEMM2: out2 = zb @ BT^T, BT = [P | muP | 0] as [896,768].
// flat grid 448, XCD swizzle: each XCD owns 56 blocks = 8 bm-panels x 7 bn.
// bn<6: zP tile -> rowdot with zb -> atomicAdd zPz[row]
// bn==6: score tile -> max_c(s - halfmPm[c]) -> smax[row]
__global__ __launch_bounds__(256, 2) void k_gemm2(const bf16* __restrict__ zb,
                                                  const bf16* __restrict__ BT,
                                                  const float* __restrict__ halfmPm,
                                                  float* __restrict__ zPz,
                                                  float* __restrict__ smax) {
  __shared__ __align__(16) bf16 As0[128 * 64], Bs0[128 * 64];
  __shared__ __align__(16) bf16 As1[128 * 64], Bs1[128 * 64];
  __shared__ float sred[2][128];
  f32x4 acc[4][4];
#pragma unroll
  for (int m = 0; m < 4; ++m)
#pragma unroll
    for (int n = 0; n < 4; ++n) acc[m][n] = (f32x4){0.f, 0.f, 0.f, 0.f};
  const int bid = blockIdx.x;                 // 0..447
  const int s = (bid & 7) * 56 + (bid >> 3);  // bijective: 448 % 8 == 0
  const long bm = s / 7, bn = s % 7;
  gemm_mainloop_pf<DD>(zb, BT, bm * 128, bn * 128, As0, Bs0, As1, Bs1, acc);
  const int tid = threadIdx.x, lane = tid & 63, w = tid >> 6;
  const int wr = w >> 1, wc = w & 1, fr = lane & 15, fq = lane >> 4;

  if (bn < 6) {
    float p[4][4];
#pragma unroll
    for (int m = 0; m < 4; ++m)
#pragma unroll
      for (int j = 0; j < 4; ++j) p[m][j] = 0.f;
#pragma unroll
    for (int m = 0; m < 4; ++m)
#pragma unroll
      for (int n = 0; n < 4; ++n)
#pragma unroll
        for (int j = 0; j < 4; ++j) {
          long row = bm * 128 + wr * 64 + m * 16 + fq * 4 + j;
          long col = bn * 128 + wc * 64 + n * 16 + fr;
          p[m][j] += acc[m][n][j] * __bfloat162float(zb[row * DD + col]);
        }
#pragma unroll
    for (int m = 0; m < 4; ++m)
#pragma unroll
      for (int j = 0; j < 4; ++j) {
        float v = p[m][j];
        v += __shfl_xor(v, 1, 64);
        v += __shfl_xor(v, 2, 64);
        v += __shfl_xor(v, 4, 64);
        v += __shfl_xor(v, 8, 64);
        if (fr == 0)
          atomicAdd(&zPz[bm * 128 + wr * 64 + m * 16 + fq * 4 + j], v);
      }
  } else {
    float hm[4];
#pragma unroll
    for (int n = 0; n < 4; ++n) hm[n] = halfmPm[wc * 64 + n * 16 + fr];
    float mx[4][4];
#pragma unroll
    for (int m = 0; m < 4; ++m)
#pragma unroll
      for (int j = 0; j < 4; ++j) mx[m][j] = -3e38f;
#pragma unroll
    for (int m = 0; m < 4; ++m)
#pragma unroll
      for (int n = 0; n < 4; ++n)
#pragma unroll
        for (int j = 0; j < 4; ++j)
          mx[m][j] = fmaxf(mx[m][j], acc[m][n][j] - hm[n]);
#pragma unroll
    for (int m = 0; m < 4; ++m)
#pragma unroll
      for (int j = 0; j < 4; ++j) {
        float v = mx[m][j];
        v = fmaxf(v, __shfl_xor(v, 1, 64));
        v = fmaxf(v, __shfl_xor(v, 2, 64));
        v = fmaxf(v, __shfl_xor(v, 4, 64));
        v = fmaxf(v, __shfl_xor(v, 8, 64));
        if (fr == 0) sred[wc][wr * 64 + m * 16 + fq * 4 + j] = v;
      }
    __syncthreads();
    if (tid < 128) smax[bm * 128 + tid] = fmaxf(sred[0][tid], sred[1][tid]);
  }
}

__global__ void k_final(const float* __restrict__ smax, const float* __restrict__ zPz,
                        float* __restrict__ out) {
  int i = blockIdx.x * 256 + threadIdx.x;
  if (i < NROWS) out[i] = smax[i] - 0.5f * zPz[i];
}

// ---------------- launch ----------------

extern "C" void kernel_launch(void* const* d_in, const int* in_sizes, int n_in,
                              void* d_out, int out_size, void* d_ws, size_t ws_size,
                              hipStream_t stream) {
  const float* x  = (const float*)d_in[0];
  const float* W  = (const float*)d_in[1];
  const float* mu = (const float*)d_in[2];
  const float* P  = (const float*)d_in[3];
  float* out = (float*)d_out;

  char* ws = (char*)d_ws;
  bf16*  Wt   = (bf16*)(ws);                       //  3,145,728
  bf16*  BT   = (bf16*)(ws + 3145728);             //  1,376,256
  bf16*  zb   = (bf16*)(ws + 4521984);             // 12,582,912
  float* hm   = (float*)(ws + 17104896);           // 512 B
  float* zPz  = (float*)(ws + 17105408);           // 32,768 B
  float* smax = (float*)(ws + 17138176);           // 32,768 B

  // hm + zPz + smax are contiguous: one memset covers all three
  hipMemsetAsync(ws + 17104896, 0, 66048, stream);
  k_transpose_W<<<dim3(24, 64), 256, 0, stream>>>(W, Wt);
  k_convert_P  <<<2688, 256, 0, stream>>>(P, BT, hm);
  k_prep_mu    <<<dim3(CCLS, 3), 256, 0, stream>>>(mu, P, BT, hm);
  k_gemm1      <<<384, 256, 0, stream>>>(x, Wt, zb);
  k_gemm2      <<<448, 256, 0, stream>>>(zb, BT, hm, zPz, smax);
  k_final      <<<32, 256, 0, stream>>>(smax, zPz, out);
}

// Round 8
// 97.033 us; speedup vs baseline: 1.8954x; 1.0577x over previous
//
#include <hip/hip_runtime.h>
#include <hip/hip_bf16.h>

typedef __attribute__((ext_vector_type(8))) short bf16x8;
typedef __attribute__((ext_vector_type(4))) float f32x4;
typedef __hip_bfloat16 bf16;

#define NROWS 8192
#define DIN   2048
#define DD    768
#define CCLS  100

// ---------------- fused prep kernel ----------------
// Block partition (all tasks independent, branch is block-uniform):
//   [0,300):      prep_mu   (c=b/3, j=b%3)   muP rows of BT + 0.5*muPmu -> hm
//   [300,1836):   transpose_W                W [2048,768] f32 -> Wt [768,2048] bf16
//   [1836,4524):  convert_P                  P -> BT rows [0,768) + pads; hm pads
//   [4524,12716): convert_x                  x f32 -> xb bf16 (8 elems/thread)
// The BW-bound convert_x overlaps the latency-bound small tasks instead of
// running after them serially; 3 launch gaps also disappear.
__global__ __launch_bounds__(256) void k_prep(const float* __restrict__ x,
                                              const float* __restrict__ W,
                                              const float* __restrict__ mu,
                                              const float* __restrict__ P,
                                              bf16* __restrict__ xb,
                                              bf16* __restrict__ Wt,
                                              bf16* __restrict__ BT,
                                              float* __restrict__ hm) {
  __shared__ float muL[DD];
  __shared__ float red[256];
  __shared__ float tile[32][33];
  const int b = blockIdx.x;
  const int tid = threadIdx.x;

  if (b < 300) {                      // ---- prep_mu ----
    const int c = b / 3, j = b % 3;
    for (int i = tid; i < DD; i += 256) muL[i] = mu[(long)c * DD + i];
    __syncthreads();
    const int col = j * 256 + tid;
    float a = 0.f;
    for (int d = 0; d < DD; ++d) a += muL[d] * P[(long)d * DD + col];
    BT[(long)(DD + c) * DD + col] = __float2bfloat16(a);
    red[tid] = a * muL[col];
    __syncthreads();
    for (int s = 128; s > 0; s >>= 1) {
      if (tid < s) red[tid] += red[tid + s];
      __syncthreads();
    }
    if (tid == 0) atomicAdd(&hm[c], 0.5f * red[0]);
  } else if (b < 1836) {              // ---- transpose_W ----
    const int t = b - 300;
    const int tx = tid & 31, ty = tid >> 5;
    const int n0 = (t % 24) * 32, k0 = (t / 24) * 32;
#pragma unroll
    for (int i = 0; i < 4; ++i)
      tile[ty + 8*i][tx] = W[(long)(k0 + ty + 8*i) * DD + n0 + tx];
    __syncthreads();
#pragma unroll
    for (int i = 0; i < 4; ++i)
      Wt[(long)(n0 + ty + 8*i) * DIN + k0 + tx] = __float2bfloat16(tile[tx][ty + 8*i]);
  } else if (b < 4524) {              // ---- convert_P ----
    const int id = (b - 1836) * 256 + tid;     // 0 .. 896*768-1
    const int r = id / DD;
    if (r < DD)                BT[id] = __float2bfloat16(P[id]);
    else if (r >= DD + CCLS)   BT[id] = __float2bfloat16(0.f);
    if (id >= CCLS && id < 128) hm[id] = 1e30f;
  } else {                            // ---- convert_x ----
    const long i = ((long)(b - 4524) * 256 + tid) * 8;
    float4 v0 = *(const float4*)(x + i);
    float4 v1 = *(const float4*)(x + i + 4);
    union { bf16 h[8]; bf16x8 v; } tcv;
    tcv.h[0] = __float2bfloat16(v0.x); tcv.h[1] = __float2bfloat16(v0.y);
    tcv.h[2] = __float2bfloat16(v0.z); tcv.h[3] = __float2bfloat16(v0.w);
    tcv.h[4] = __float2bfloat16(v1.x); tcv.h[5] = __float2bfloat16(v1.y);
    tcv.h[6] = __float2bfloat16(v1.z); tcv.h[7] = __float2bfloat16(v1.w);
    *(bf16x8*)(xb + i) = tcv.v;
  }
}

// ---------------- GEMM core (R6-verified: 128x128, BK=64, 4 waves, 2ph dbuf, T1+T2) --
// T2 layout invariant (both-sides-or-neither, rule #21):
//   LDS[row][s'] = G[row][s' ^ (row&7)]  (s' = 16B slot, 8 slots/row);
//   global_load_lds keeps a LINEAR dest, the permutation is applied to the per-lane
//   global SOURCE slot (sc); reads use slot' = fq ^ (kk>>3) ^ (fr&7) (row&7==fr&7).

#define STAGE(As_, Bs_, kt_)                                                            \
  do {                                                                                  \
    _Pragma("unroll")                                                                   \
    for (int i = 0; i < 4; ++i) {                                                       \
      const int rr = i * 32 + w * 8;                                                    \
      const bf16* gA = A + (rowA0 + rr + sr) * (long)LDK + (kt_) + sc;                  \
      const bf16* gB = B + (rowB0 + rr + sr) * (long)LDK + (kt_) + sc;                  \
      __builtin_amdgcn_global_load_lds(                                                 \
          (const __attribute__((address_space(1))) unsigned int*)gA,                    \
          (__attribute__((address_space(3))) unsigned int*)((As_) + rr * 64), 16, 0, 0);\
      __builtin_amdgcn_global_load_lds(                                                 \
          (const __attribute__((address_space(1))) unsigned int*)gB,                    \
          (__attribute__((address_space(3))) unsigned int*)((Bs_) + rr * 64), 16, 0, 0);\
    }                                                                                   \
  } while (0)

#define COMPUTE(As_, Bs_)                                                               \
  do {                                                                                  \
    _Pragma("unroll")                                                                   \
    for (int kk = 0; kk < 64; kk += 32) {                                               \
      const int slot = (fq ^ (kk >> 3) ^ (fr & 7)) * 8;  /* swizzled 16B slot */        \
      bf16x8 av[4], bv[4];                                                              \
      _Pragma("unroll")                                                                 \
      for (int m = 0; m < 4; ++m)                                                       \
        av[m] = *(const bf16x8*)((As_) + (wr * 64 + m * 16 + fr) * 64 + slot);          \
      _Pragma("unroll")                                                                 \
      for (int n = 0; n < 4; ++n)                                                       \
        bv[n] = *(const bf16x8*)((Bs_) + (wc * 64 + n * 16 + fr) * 64 + slot);          \
      _Pragma("unroll")                                                                 \
      for (int m = 0; m < 4; ++m)                                                       \
        _Pragma("unroll")                                                               \
        for (int n = 0; n < 4; ++n)                                                     \
          acc[m][n] = __builtin_amdgcn_mfma_f32_16x16x32_bf16(av[m], bv[n],             \
                                                              acc[m][n], 0, 0, 0);      \
    }                                                                                   \
  } while (0)

template<int LDK>
__device__ __forceinline__ void gemm_mainloop_pf(
    const bf16* __restrict__ A, const bf16* __restrict__ B,
    long rowA0, long rowB0,
    bf16* As0, bf16* Bs0, bf16* As1, bf16* Bs1, f32x4 acc[4][4])
{
  const int tid  = threadIdx.x;
  const int lane = tid & 63;
  const int w    = tid >> 6;            // 0..3
  const int wr = w >> 1, wc = w & 1;
  const int fr = lane & 15, fq = lane >> 4;
  const int sr = lane >> 3;                      // staging row within 8-row chunk (0..7)
  const int sc = (((lane & 7) ^ sr) * 8);        // inverse-swizzled global 16B slot

  STAGE(As0, Bs0, 0);
#pragma unroll 1
  for (int kt = 0; kt < LDK; kt += 128) {
    __syncthreads();                          // buf0 staged + all waves synced
    if (kt + 64 < LDK) STAGE(As1, Bs1, kt + 64);
    COMPUTE(As0, Bs0);
    __syncthreads();                          // buf1 staged + reads of buf0 done
    if (kt + 128 < LDK) STAGE(As0, Bs0, kt + 128);
    COMPUTE(As1, Bs1);
  }
}

// GEMM1: zb = xb @ Wt^T   [8192,2048]x[768,2048]^T -> bf16 [8192,768]
// flat grid 384, XCD swizzle: each XCD owns 48 blocks = 8 bm-panels x 6 bn.
__global__ __launch_bounds__(256, 2) void k_gemm1(const bf16* __restrict__ xb,
                                                  const bf16* __restrict__ Wt,
                                                  bf16* __restrict__ zb) {
  __shared__ __align__(16) bf16 As0[128 * 64], Bs0[128 * 64];
  __shared__ __align__(16) bf16 As1[128 * 64], Bs1[128 * 64];
  f32x4 acc[4][4];
#pragma unroll
  for (int m = 0; m < 4; ++m)
#pragma unroll
    for (int n = 0; n < 4; ++n) acc[m][n] = (f32x4){0.f, 0.f, 0.f, 0.f};
  const int bid = blockIdx.x;                 // 0..383
  const int s = (bid & 7) * 48 + (bid >> 3);  // bijective: 384 % 8 == 0
  const long bm = s / 6, bn = s % 6;
  gemm_mainloop_pf<DIN>(xb, Wt, bm * 128, bn * 128, As0, Bs0, As1, Bs1, acc);
  const int tid = threadIdx.x, lane = tid & 63, w = tid >> 6;
  const int wr = w >> 1, wc = w & 1, fr = lane & 15, fq = lane >> 4;
#pragma unroll
  for (int m = 0; m < 4; ++m)
#pragma unroll
    for (int n = 0; n < 4; ++n)
#pragma unroll
      for (int j = 0; j < 4; ++j) {
        long row = bm * 128 + wr * 64 + m * 16 + fq * 4 + j;
        long col = bn * 128 + wc * 64 + n * 16 + fr;
        zb[row * DD + col] = __float2bfloat16(acc[m][n][j]);
      }
}

// GEMM2: out2 = zb @ BT^T, BT = [P | muP | 0] as [896,768].
// flat grid 448, XCD swizzle: each XCD owns 56 blocks = 8 bm-panels x 7 bn.
// bn<6: zP tile -> rowdot with zb -> atomicAdd zPz[row]
// bn==6: score tile -> max_c(s - halfmPm[c]) -> smax[row]
__global__ __launch_bounds__(256, 2) void k_gemm2(const bf16* __restrict__ zb,
                                                  const bf16* __restrict__ BT,
                                                  const float* __restrict__ halfmPm,
                                                  float* __restrict__ zPz,
                                                  float* __restrict__ smax) {
  __shared__ __align__(16) bf16 As0[128 * 64], Bs0[128 * 64];
  __shared__ __align__(16) bf16 As1[128 * 64], Bs1[128 * 64];
  __shared__ float sred[2][128];
  f32x4 acc[4][4];
#pragma unroll
  for (int m = 0; m < 4; ++m)
#pragma unroll
    for (int n = 0; n < 4; ++n) acc[m][n] = (f32x4){0.f, 0.f, 0.f, 0.f};
  const int bid = blockIdx.x;                 // 0..447
  const int s = (bid & 7) * 56 + (bid >> 3);  // bijective: 448 % 8 == 0
  const long bm = s / 7, bn = s % 7;
  gemm_mainloop_pf<DD>(zb, BT, bm * 128, bn * 128, As0, Bs0, As1, Bs1, acc);
  const int tid = threadIdx.x, lane = tid & 63, w = tid >> 6;
  const int wr = w >> 1, wc = w & 1, fr = lane & 15, fq = lane >> 4;

  if (bn < 6) {
    float p[4][4];
#pragma unroll
    for (int m = 0; m < 4; ++m)
#pragma unroll
      for (int j = 0; j < 4; ++j) p[m][j] = 0.f;
#pragma unroll
    for (int m = 0; m < 4; ++m)
#pragma unroll
      for (int n = 0; n < 4; ++n)
#pragma unroll
        for (int j = 0; j < 4; ++j) {
          long row = bm * 128 + wr * 64 + m * 16 + fq * 4 + j;
          long col = bn * 128 + wc * 64 + n * 16 + fr;
          p[m][j] += acc[m][n][j] * __bfloat162float(zb[row * DD + col]);
        }
#pragma unroll
    for (int m = 0; m < 4; ++m)
#pragma unroll
      for (int j = 0; j < 4; ++j) {
        float v = p[m][j];
        v += __shfl_xor(v, 1, 64);
        v += __shfl_xor(v, 2, 64);
        v += __shfl_xor(v, 4, 64);
        v += __shfl_xor(v, 8, 64);
        if (fr == 0)
          atomicAdd(&zPz[bm * 128 + wr * 64 + m * 16 + fq * 4 + j], v);
      }
  } else {
    float hm[4];
#pragma unroll
    for (int n = 0; n < 4; ++n) hm[n] = halfmPm[wc * 64 + n * 16 + fr];
    float mx[4][4];
#pragma unroll
    for (int m = 0; m < 4; ++m)
#pragma unroll
      for (int j = 0; j < 4; ++j) mx[m][j] = -3e38f;
#pragma unroll
    for (int m = 0; m < 4; ++m)
#pragma unroll
      for (int n = 0; n < 4; ++n)
#pragma unroll
        for (int j = 0; j < 4; ++j)
          mx[m][j] = fmaxf(mx[m][j], acc[m][n][j] - hm[n]);
#pragma unroll
    for (int m = 0; m < 4; ++m)
#pragma unroll
      for (int j = 0; j < 4; ++j) {
        float v = mx[m][j];
        v = fmaxf(v, __shfl_xor(v, 1, 64));
        v = fmaxf(v, __shfl_xor(v, 2, 64));
        v = fmaxf(v, __shfl_xor(v, 4, 64));
        v = fmaxf(v, __shfl_xor(v, 8, 64));
        if (fr == 0) sred[wc][wr * 64 + m * 16 + fq * 4 + j] = v;
      }
    __syncthreads();
    if (tid < 128) smax[bm * 128 + tid] = fmaxf(sred[0][tid], sred[1][tid]);
  }
}

__global__ void k_final(const float* __restrict__ smax, const float* __restrict__ zPz,
                        float* __restrict__ out) {
  int i = blockIdx.x * 256 + threadIdx.x;
  if (i < NROWS) out[i] = smax[i] - 0.5f * zPz[i];
}

// ---------------- launch ----------------

extern "C" void kernel_launch(void* const* d_in, const int* in_sizes, int n_in,
                              void* d_out, int out_size, void* d_ws, size_t ws_size,
                              hipStream_t stream) {
  const float* x  = (const float*)d_in[0];
  const float* W  = (const float*)d_in[1];
  const float* mu = (const float*)d_in[2];
  const float* P  = (const float*)d_in[3];
  float* out = (float*)d_out;

  char* ws = (char*)d_ws;
  bf16*  xb   = (bf16*)(ws);                       // 33,554,432
  bf16*  Wt   = (bf16*)(ws + 33554432);            //  3,145,728
  bf16*  BT   = (bf16*)(ws + 36700160);            //  1,376,256
  bf16*  zb   = (bf16*)(ws + 38076416);            // 12,582,912
  float* hm   = (float*)(ws + 50659328);           // 512 B
  float* zPz  = (float*)(ws + 50659840);           // 32,768 B
  float* smax = (float*)(ws + 50692608);           // 32,768 B

  // hm + zPz + smax are contiguous: one memset covers all three
  hipMemsetAsync(ws + 50659328, 0, 66048, stream);
  k_prep  <<<12716, 256, 0, stream>>>(x, W, mu, P, xb, Wt, BT, hm);
  k_gemm1 <<<384, 256, 0, stream>>>(xb, Wt, zb);
  k_gemm2 <<<448, 256, 0, stream>>>(zb, BT, hm, zPz, smax);
  k_final <<<32, 256, 0, stream>>>(smax, zPz, out);
}